// Round 4
// baseline (2816.673 us; speedup 1.0000x reference)
//
#include <hip/hip_runtime.h>
#include <hip/hip_bf16.h>
#include <stdint.h>

#define BATCH 8
#define NPTS  16384
#define DIMF  64
#define SPTS  1024
#define NSAMP 32
#define MTOT  (BATCH*SPTS*NSAMP)   // 262144

__device__ __forceinline__ float bfu_lo(uint32_t u){ return __uint_as_float(u<<16); }
__device__ __forceinline__ float bfu_hi(uint32_t u){ return __uint_as_float(u & 0xffff0000u); }
__device__ __forceinline__ uint16_t f2bf(float f){
  __hip_bfloat16 h = __float2bfloat16(f);
  uint16_t u; __builtin_memcpy(&u, &h, 2); return u;
}

// ---------------- prep: transpose points (B,64,N)->(B,N,64) ----------------
__global__ __launch_bounds__(256) void transpose_kernel(const float* __restrict__ pts,
                                                        float* __restrict__ ptsT){
  __shared__ float tile[32][33];
  int b = blockIdx.z;
  int n0 = blockIdx.x*32, c0 = blockIdx.y*32;
  int tx = threadIdx.x & 31, ty = threadIdx.x >> 5;
  const float* src = pts + (size_t)b*DIMF*NPTS;
  float* dst = ptsT + (size_t)b*NPTS*DIMF;
#pragma unroll
  for (int j=0;j<4;j++)
    tile[ty+8*j][tx] = src[(size_t)(c0+ty+8*j)*NPTS + n0 + tx];
  __syncthreads();
#pragma unroll
  for (int j=0;j<4;j++)
    dst[(size_t)(n0+ty+8*j)*DIMF + c0 + tx] = tile[tx][ty+8*j];
}

// ---------------- FPS: 1 block (1024 thr) per batch, bit-exact f32 (passes) ----------------
__global__ __launch_bounds__(1024) void fps_kernel(const float* __restrict__ xyz,
                                                   float* __restrict__ out0){
  int b = blockIdx.x;
  const float* X = xyz + (size_t)b*3*NPTS;
  int t = threadIdx.x;
  int lane = t & 63, wid = t >> 6;
  float px[16], py[16], pz[16], dst[16];
#pragma unroll
  for (int k=0;k<16;k++){
    int n = t + (k<<10);
    px[k]=X[n]; py[k]=X[NPTS+n]; pz[k]=X[2*NPTS+n];
    dst[k]=1e10f;
  }
  __shared__ float rv[16];
  __shared__ int   ri[16];
  __shared__ int   far_sh;
  int far = 0;
  float* o = out0 + (size_t)b*3*SPTS;
  for (int s=0;s<SPTS;s++){
    float cx = X[far], cy = X[NPTS+far], cz = X[2*NPTS+far];
    if (t==0){ o[s]=cx; o[SPTS+s]=cy; o[2*SPTS+s]=cz; }
    if (s==SPTS-1) break;
    float best = -1.0f; int bi = 0x7fffffff;
#pragma unroll
    for (int k=0;k<16;k++){
      float dx=__fsub_rn(px[k],cx), dy=__fsub_rn(py[k],cy), dz=__fsub_rn(pz[k],cz);
      float d = __fadd_rn(__fadd_rn(__fmul_rn(dx,dx),__fmul_rn(dy,dy)),__fmul_rn(dz,dz));
      d = fminf(dst[k], d); dst[k] = d;
      if (d > best){ best = d; bi = t + (k<<10); }   // ascending n in k -> first-max
    }
#pragma unroll
    for (int off=1; off<64; off<<=1){
      float ov = __shfl_xor(best, off);
      int   oi = __shfl_xor(bi, off);
      if (ov > best || (ov == best && oi < bi)){ best = ov; bi = oi; }
    }
    if (lane==0){ rv[wid]=best; ri[wid]=bi; }
    __syncthreads();
    if (wid==0){
      float v = (lane<16) ? rv[lane] : -2.0f;
      int   j = (lane<16) ? ri[lane] : 0x7fffffff;
#pragma unroll
      for (int off=1; off<16; off<<=1){
        float ov = __shfl_xor(v, off);
        int   oi = __shfl_xor(j, off);
        if (ov > v || (ov == v && oi < j)){ v = ov; j = oi; }
      }
      if (lane==0) far_sh = j;
    }
    __syncthreads();
    far = far_sh;
  }
}

// ---------------- ball query: XLA-CPU f32 replication ----------------
// A (query norm), B (point norm): plain sequential ((x^2+y^2)+z^2)  [XLA reduce, no FMA]
// C (dot): Eigen gemm FMA chain fma(z*nz, fma(y*ny, x*nx))          [einsum -> Eigen]
// sqr = (A+B) - 2*C  (x2 exact, fuse-independent)
__global__ __launch_bounds__(256) void ball_kernel(const float* __restrict__ xyz,
                                                   const float* __restrict__ newxyz,
                                                   int* __restrict__ idxo){
  int b  = blockIdx.x >> 5;
  int sc = blockIdx.x & 31;           // 32 s per block
  const float* X  = xyz + (size_t)b*3*NPTS;
  int t = threadIdx.x, lane = t & 63, w = t >> 6;
  __shared__ float lx[512], ly[512], lz[512], ls[512];
  __shared__ int done;
  if (t==0) done = 0;
  const float rsq = 0.01f;
  float nx[8], ny[8], nz[8], sn[8];
  int cnt[8], first[8];
  int sbase = sc*32 + w*8;
#pragma unroll
  for (int q=0;q<8;q++){
    int s = sbase + q;
    nx[q] = newxyz[(size_t)b*3*SPTS + s];
    ny[q] = newxyz[(size_t)b*3*SPTS + SPTS + s];
    nz[q] = newxyz[(size_t)b*3*SPTS + 2*SPTS + s];
    sn[q] = __fadd_rn(__fadd_rn(__fmul_rn(nx[q],nx[q]),__fmul_rn(ny[q],ny[q])),
                      __fmul_rn(nz[q],nz[q]));
    cnt[q]=0; first[q]=0;
  }
  __syncthreads();
  for (int T=0;T<32;T++){
    {
      float ax = X[T*512 + t], ay = X[NPTS + T*512 + t], az = X[2*NPTS + T*512 + t];
      lx[t]=ax; ly[t]=ay; lz[t]=az;
      ls[t] = __fadd_rn(__fadd_rn(__fmul_rn(ax,ax),__fmul_rn(ay,ay)),__fmul_rn(az,az));
      float bx = X[T*512 + t + 256], by = X[NPTS + T*512 + t + 256], bz = X[2*NPTS + T*512 + t + 256];
      lx[t+256]=bx; ly[t+256]=by; lz[t+256]=bz;
      ls[t+256] = __fadd_rn(__fadd_rn(__fmul_rn(bx,bx),__fmul_rn(by,by)),__fmul_rn(bz,bz));
    }
    __syncthreads();
#pragma unroll
    for (int q=0;q<8;q++){
      if (cnt[q] >= NSAMP) continue;
      int s = sbase + q;
      int* op = idxo + ((size_t)(b*SPTS + s))*NSAMP;
      for (int c=0;c<8;c++){
        int li = c*64 + lane;
        // Eigen FMA-accumulate over k: ((nx*x) fma ny*y) fma nz*z
        float dot = fmaf(nz[q], lz[li], fmaf(ny[q], ly[li], __fmul_rn(nx[q], lx[li])));
        float sq  = __fsub_rn(__fadd_rn(sn[q], ls[li]), __fmul_rn(2.0f, dot));
        bool in = (sq <= rsq);
        unsigned long long m = __ballot(in);
        if (cnt[q]==0 && m) first[q] = T*512 + c*64 + (int)__builtin_ctzll(m);
        if (in){
          int slot = cnt[q] + (int)__popcll(m & ((1ull<<lane)-1ull));
          if (slot < NSAMP) op[slot] = T*512 + li;
        }
        cnt[q] += (int)__popcll(m);
        if (cnt[q] >= NSAMP){ if (lane==0) atomicAdd(&done,1); break; }
      }
    }
    __syncthreads();
    if (done >= 32) break;   // uniform across the block
  }
#pragma unroll
  for (int q=0;q<8;q++){
    if (cnt[q] < NSAMP){
      int s = sbase + q;
      int* op = idxo + ((size_t)(b*SPTS + s))*NSAMP;
      if (lane >= cnt[q] && lane < NSAMP) op[lane] = first[q];
    }
  }
}

// ---------------- GEMM1: fused gather (xyz diff + pts) x w1 -> y1 (bf16) ----------------
__global__ __launch_bounds__(256) void gemm1_kernel(const float* __restrict__ xyz,
                                                    const float* __restrict__ ptsT,
                                                    const int* __restrict__ idx,
                                                    const float* __restrict__ newxyz,
                                                    const float* __restrict__ w1,
                                                    const float* __restrict__ b1,
                                                    uint16_t* __restrict__ y1){
  __shared__ float As[128*69];
  __shared__ float Ws[67*64];
  __shared__ float bias[64];
  __shared__ int   ndx[128];
  __shared__ float nxs[4][3];
  int t = threadIdx.x;
  int g0 = blockIdx.x*128;
  if (t < 128) ndx[t] = idx[g0 + t];
  if (t < 12){
    int grp = t/3, c = t%3;
    int bs = (g0>>5) + grp; int b = bs>>10, s = bs & 1023;
    nxs[grp][c] = newxyz[(size_t)b*3*SPTS + c*SPTS + s];
  }
  if (t < 64) bias[t] = b1[t];
  for (int e=t; e<67*64; e+=256){ int k=e>>6, c=e&63; Ws[k*64+c] = w1[c*67+k]; }
  __syncthreads();
  {
    int r = t>>1, h = t&1;
    int n = ndx[r];
    int bs = (g0>>5) + (r>>5); int b = bs>>10;
    const float* pr = ptsT + ((size_t)(b*NPTS + n))*64 + h*32;
    float* ar = As + r*69;
    if (h==0){
      int grp = r>>5;
      ar[0] = __fsub_rn(xyz[(size_t)b*3*NPTS + n],          nxs[grp][0]);
      ar[1] = __fsub_rn(xyz[(size_t)b*3*NPTS + NPTS + n],   nxs[grp][1]);
      ar[2] = __fsub_rn(xyz[(size_t)b*3*NPTS + 2*NPTS + n], nxs[grp][2]);
    }
    float* ap = ar + 3 + h*32;
#pragma unroll
    for (int j=0;j<8;j++){
      float4 v = *(const float4*)(pr + j*4);
      ap[j*4+0]=v.x; ap[j*4+1]=v.y; ap[j*4+2]=v.z; ap[j*4+3]=v.w;
    }
  }
  __syncthreads();
  int rg = t>>3, cg = t&7;
  float acc[4][8];
#pragma unroll
  for (int i=0;i<4;i++)
#pragma unroll
    for (int j=0;j<8;j++) acc[i][j]=0.f;
  for (int k=0;k<67;k++){
    float a0 = As[(rg*4+0)*69+k];
    float a1 = As[(rg*4+1)*69+k];
    float a2 = As[(rg*4+2)*69+k];
    float a3 = As[(rg*4+3)*69+k];
    const float* wr = Ws + k*64 + cg*8;
    float4 w0 = *(const float4*)wr;
    float4 w1v = *(const float4*)(wr+4);
    float wj[8] = {w0.x,w0.y,w0.z,w0.w,w1v.x,w1v.y,w1v.z,w1v.w};
#pragma unroll
    for (int j=0;j<8;j++){
      acc[0][j] = fmaf(a0, wj[j], acc[0][j]);
      acc[1][j] = fmaf(a1, wj[j], acc[1][j]);
      acc[2][j] = fmaf(a2, wj[j], acc[2][j]);
      acc[3][j] = fmaf(a3, wj[j], acc[3][j]);
    }
  }
#pragma unroll
  for (int i=0;i<4;i++){
    int gr = g0 + rg*4 + i;
    uint16_t* yr = y1 + (size_t)gr*64 + cg*8;
    uint4 vv;
    uint32_t u[4];
#pragma unroll
    for (int j=0;j<4;j++){
      float v0 = acc[i][2*j]   + bias[cg*8+2*j];
      float v1 = acc[i][2*j+1] + bias[cg*8+2*j+1];
      u[j] = (uint32_t)f2bf(v0) | ((uint32_t)f2bf(v1)<<16);
    }
    vv.x=u[0]; vv.y=u[1]; vv.z=u[2]; vv.w=u[3];
    *(uint4*)yr = vv;
  }
}

// ---------------- GEMM2: relu(bn(y1)) x w2 -> y2 (bf16), K=64 ----------------
__global__ __launch_bounds__(256) void gemm2_kernel(const uint16_t* __restrict__ yin,
                                                    const float* __restrict__ w2,
                                                    const float* __restrict__ b2,
                                                    const float* __restrict__ scale,
                                                    const float* __restrict__ shift,
                                                    uint16_t* __restrict__ yout){
  __shared__ float As[128*65];
  __shared__ float Ws[64*64];
  __shared__ float bias[64], sc[64], sh[64];
  int t = threadIdx.x;
  int g0 = blockIdx.x*128;
  if (t < 64){ bias[t]=b2[t]; sc[t]=scale[t]; sh[t]=shift[t]; }
  for (int e=t; e<64*64; e+=256){ int k=e>>6, c=e&63; Ws[k*64+c] = w2[c*64+k]; }
  __syncthreads();
  {
    int r = t>>1, h = t&1;
    const uint4* yv = (const uint4*)(yin + (size_t)(g0+r)*64 + h*32);
    float* ar = As + r*65 + h*32;
#pragma unroll
    for (int j=0;j<4;j++){
      uint4 u = yv[j];
      uint32_t vv[4] = {u.x,u.y,u.z,u.w};
#pragma unroll
      for (int m=0;m<4;m++){
        int c = h*32 + j*8 + m*2;
        ar[j*8+m*2]   = fmaxf(fmaf(bfu_lo(vv[m]), sc[c],   sh[c]),   0.f);
        ar[j*8+m*2+1] = fmaxf(fmaf(bfu_hi(vv[m]), sc[c+1], sh[c+1]), 0.f);
      }
    }
  }
  __syncthreads();
  int rg = t>>3, cg = t&7;
  float acc[4][8];
#pragma unroll
  for (int i=0;i<4;i++)
#pragma unroll
    for (int j=0;j<8;j++) acc[i][j]=0.f;
  for (int k=0;k<64;k++){
    float a0 = As[(rg*4+0)*65+k];
    float a1 = As[(rg*4+1)*65+k];
    float a2 = As[(rg*4+2)*65+k];
    float a3 = As[(rg*4+3)*65+k];
    const float* wr = Ws + k*64 + cg*8;
    float4 w0 = *(const float4*)wr;
    float4 w1v = *(const float4*)(wr+4);
    float wj[8] = {w0.x,w0.y,w0.z,w0.w,w1v.x,w1v.y,w1v.z,w1v.w};
#pragma unroll
    for (int j=0;j<8;j++){
      acc[0][j] = fmaf(a0, wj[j], acc[0][j]);
      acc[1][j] = fmaf(a1, wj[j], acc[1][j]);
      acc[2][j] = fmaf(a2, wj[j], acc[2][j]);
      acc[3][j] = fmaf(a3, wj[j], acc[3][j]);
    }
  }
#pragma unroll
  for (int i=0;i<4;i++){
    int gr = g0 + rg*4 + i;
    uint16_t* yr = yout + (size_t)gr*64 + cg*8;
    uint4 vv; uint32_t u[4];
#pragma unroll
    for (int j=0;j<4;j++){
      float v0 = acc[i][2*j]   + bias[cg*8+2*j];
      float v1 = acc[i][2*j+1] + bias[cg*8+2*j+1];
      u[j] = (uint32_t)f2bf(v0) | ((uint32_t)f2bf(v1)<<16);
    }
    vv.x=u[0]; vv.y=u[1]; vv.z=u[2]; vv.w=u[3];
    *(uint4*)yr = vv;
  }
}

// ---------------- GEMM3: relu(bn(y2)) x w3 -> y3 (bf16), K=64, OUT=128 ----------------
__global__ __launch_bounds__(256) void gemm3_kernel(const uint16_t* __restrict__ yin,
                                                    const float* __restrict__ w3,
                                                    const float* __restrict__ b3,
                                                    const float* __restrict__ scale,
                                                    const float* __restrict__ shift,
                                                    uint16_t* __restrict__ yout){
  __shared__ float As[64*65];
  __shared__ float Ws[64*128];
  __shared__ float bias[128], sc[64], sh[64];
  int t = threadIdx.x;
  int g0 = blockIdx.x*64;
  if (t < 128) bias[t]=b3[t];
  if (t < 64){ sc[t]=scale[t]; sh[t]=shift[t]; }
  for (int e=t; e<64*128; e+=256){ int k=e>>7, c=e&127; Ws[k*128+c] = w3[c*64+k]; }
  __syncthreads();
  {
    int r = t>>2, h = t&3;
    const uint4* yv = (const uint4*)(yin + (size_t)(g0+r)*64 + h*16);
    float* ar = As + r*65 + h*16;
#pragma unroll
    for (int j=0;j<2;j++){
      uint4 u = yv[j];
      uint32_t vv[4] = {u.x,u.y,u.z,u.w};
#pragma unroll
      for (int m=0;m<4;m++){
        int c = h*16 + j*8 + m*2;
        ar[j*8+m*2]   = fmaxf(fmaf(bfu_lo(vv[m]), sc[c],   sh[c]),   0.f);
        ar[j*8+m*2+1] = fmaxf(fmaf(bfu_hi(vv[m]), sc[c+1], sh[c+1]), 0.f);
      }
    }
  }
  __syncthreads();
  int rg = t>>4, cg = t&15;
  float acc[4][8];
#pragma unroll
  for (int i=0;i<4;i++)
#pragma unroll
    for (int j=0;j<8;j++) acc[i][j]=0.f;
  for (int k=0;k<64;k++){
    float a0 = As[(rg*4+0)*65+k];
    float a1 = As[(rg*4+1)*65+k];
    float a2 = As[(rg*4+2)*65+k];
    float a3 = As[(rg*4+3)*65+k];
    const float* wr = Ws + k*128 + cg*8;
    float4 w0 = *(const float4*)wr;
    float4 w1v = *(const float4*)(wr+4);
    float wj[8] = {w0.x,w0.y,w0.z,w0.w,w1v.x,w1v.y,w1v.z,w1v.w};
#pragma unroll
    for (int j=0;j<8;j++){
      acc[0][j] = fmaf(a0, wj[j], acc[0][j]);
      acc[1][j] = fmaf(a1, wj[j], acc[1][j]);
      acc[2][j] = fmaf(a2, wj[j], acc[2][j]);
      acc[3][j] = fmaf(a3, wj[j], acc[3][j]);
    }
  }
#pragma unroll
  for (int i=0;i<4;i++){
    int gr = g0 + rg*4 + i;
    uint16_t* yr = yout + (size_t)gr*128 + cg*8;
    uint4 vv; uint32_t u[4];
#pragma unroll
    for (int j=0;j<4;j++){
      float v0 = acc[i][2*j]   + bias[cg*8+2*j];
      float v1 = acc[i][2*j+1] + bias[cg*8+2*j+1];
      u[j] = (uint32_t)f2bf(v0) | ((uint32_t)f2bf(v1)<<16);
    }
    vv.x=u[0]; vv.y=u[1]; vv.z=u[2]; vv.w=u[3];
    *(uint4*)yr = vv;
  }
}

// ---------------- per-channel stats (sum, sumsq) ----------------
template<int C>
__global__ __launch_bounds__(256) void stats_kernel(const uint16_t* __restrict__ y,
                                                    float* __restrict__ gsum,
                                                    float* __restrict__ gsq){
  constexpr int CP  = C/2;
  constexpr int RSL = 256/CP;
  int t = threadIdx.x;
  int c0 = t % CP, rs = t / CP;
  float s0=0.f,q0=0.f,s1=0.f,q1=0.f;
#pragma unroll 4
  for (int i=0;i<512/RSL;i++){
    int r = blockIdx.x*512 + rs + i*RSL;
    uint32_t u = *(const uint32_t*)(y + (size_t)r*C + 2*c0);
    float v0 = bfu_lo(u), v1 = bfu_hi(u);
    s0 += v0; q0 += v0*v0; s1 += v1; q1 += v1*v1;
  }
  __shared__ float red[4][256];
  red[0][t]=s0; red[1][t]=q0; red[2][t]=s1; red[3][t]=q1;
  __syncthreads();
  if (t < CP){
    float a0=0,a1=0,a2=0,a3=0;
    for (int k=0;k<RSL;k++){
      a0+=red[0][k*CP+t]; a1+=red[1][k*CP+t]; a2+=red[2][k*CP+t]; a3+=red[3][k*CP+t];
    }
    atomicAdd(&gsum[2*t],   a0); atomicAdd(&gsq[2*t],   a1);
    atomicAdd(&gsum[2*t+1], a2); atomicAdd(&gsq[2*t+1], a3);
  }
}

__global__ void finalize_kernel(const float* __restrict__ gsum, const float* __restrict__ gsq,
                                const float* __restrict__ g, const float* __restrict__ be,
                                float* __restrict__ scale, float* __restrict__ shift, int C){
  int c = threadIdx.x;
  if (c >= C) return;
  double mean = (double)gsum[c] / (double)MTOT;
  double var  = (double)gsq[c] / (double)MTOT - mean*mean;
  double s    = (double)g[c] / sqrt(var + 1e-5);
  scale[c] = (float)s;
  shift[c] = (float)((double)be[c] - mean*s);
}

// ---------------- bn3 + relu + maxpool over nsample + transpose ----------------
__global__ __launch_bounds__(256) void maxpool_kernel(const uint16_t* __restrict__ y3,
                                                      const float* __restrict__ scale,
                                                      const float* __restrict__ shift,
                                                      float* __restrict__ out1){
  __shared__ float tr[16][129];
  int t = threadIdx.x;
  int b = blockIdx.x >> 6;
  int s0 = (blockIdx.x & 63) * 16;
  int ch = t & 127, sl0 = t >> 7;
  float scv = scale[ch], shv = shift[ch];
  for (int sl=sl0; sl<16; sl+=2){
    int bs = b*SPTS + s0 + sl;
    const uint16_t* yr = y3 + (size_t)bs*NSAMP*128 + ch;
    float m = 0.0f;
#pragma unroll 4
    for (int k=0;k<NSAMP;k++){
      float v = __uint_as_float(((uint32_t)yr[k*128])<<16);
      float z = fmaxf(fmaf(v, scv, shv), 0.f);
      m = fmaxf(m, z);
    }
    tr[sl][ch] = m;
  }
  __syncthreads();
  int ch2 = t >> 1, hh = t & 1;
  float vals[8];
#pragma unroll
  for (int i=0;i<8;i++) vals[i] = tr[hh*8+i][ch2];
  float* op = out1 + (size_t)b*131072 + (size_t)ch2*1024 + s0 + hh*8;
  float4 v0; v0.x=vals[0]; v0.y=vals[1]; v0.z=vals[2]; v0.w=vals[3];
  float4 v1; v1.x=vals[4]; v1.y=vals[5]; v1.z=vals[6]; v1.w=vals[7];
  *(float4*)op = v0;
  *(float4*)(op+4) = v1;
}

extern "C" void kernel_launch(void* const* d_in, const int* in_sizes, int n_in,
                              void* d_out, int out_size, void* d_ws, size_t ws_size,
                              hipStream_t stream){
  (void)in_sizes; (void)n_in; (void)out_size; (void)ws_size;
  const float* xyz = (const float*)d_in[0];
  const float* pts = (const float*)d_in[1];
  const float* w1 = (const float*)d_in[2];  const float* b1 = (const float*)d_in[3];
  const float* g1 = (const float*)d_in[4];  const float* be1 = (const float*)d_in[5];
  const float* w2 = (const float*)d_in[6];  const float* b2 = (const float*)d_in[7];
  const float* g2 = (const float*)d_in[8];  const float* be2 = (const float*)d_in[9];
  const float* w3 = (const float*)d_in[10]; const float* b3 = (const float*)d_in[11];
  const float* g3 = (const float*)d_in[12]; const float* be3 = (const float*)d_in[13];

  float* out0 = (float*)d_out;                 // (B,3,1024)
  float* out1 = out0 + BATCH*3*SPTS;           // (B,128,1024)

  char* ws = (char*)d_ws;
  float*    ptsT = (float*)(ws + 0);                       // 33,554,432 B
  int*      idx  = (int*)  (ws + 34078720);                //  1,048,576 B
  uint16_t* y1   = (uint16_t*)(ws + 35127296);             // 33,554,432 B
  uint16_t* y2   = (uint16_t*)(ws + 68681728);             // 33,554,432 B
  uint16_t* y3   = (uint16_t*)(ws + 102236160);            // 67,108,864 B
  float*    stats = (float*)(ws + 169345024);              // 1536 floats
  float* gsum1 = stats;        float* gsq1 = stats + 128;
  float* gsum2 = stats + 256;  float* gsq2 = stats + 384;
  float* gsum3 = stats + 512;  float* gsq3 = stats + 640;
  float* scale1 = stats + 768; float* shift1 = stats + 896;
  float* scale2 = stats + 1024; float* shift2 = stats + 1152;
  float* scale3 = stats + 1280; float* shift3 = stats + 1408;

  hipMemsetAsync(stats, 0, 768*sizeof(float), stream);

  transpose_kernel<<<dim3(NPTS/32, DIMF/32, BATCH), 256, 0, stream>>>(pts, ptsT);
  fps_kernel<<<BATCH, 1024, 0, stream>>>(xyz, out0);
  ball_kernel<<<BATCH*32, 256, 0, stream>>>(xyz, out0, idx);
  gemm1_kernel<<<MTOT/128, 256, 0, stream>>>(xyz, ptsT, idx, out0, w1, b1, y1);
  stats_kernel<64><<<512, 256, 0, stream>>>(y1, gsum1, gsq1);
  finalize_kernel<<<1, 128, 0, stream>>>(gsum1, gsq1, g1, be1, scale1, shift1, 64);
  gemm2_kernel<<<MTOT/128, 256, 0, stream>>>(y1, w2, b2, scale1, shift1, y2);
  stats_kernel<64><<<512, 256, 0, stream>>>(y2, gsum2, gsq2);
  finalize_kernel<<<1, 128, 0, stream>>>(gsum2, gsq2, g2, be2, scale2, shift2, 64);
  gemm3_kernel<<<MTOT/64, 256, 0, stream>>>(y2, w3, b3, scale2, shift2, y3);
  stats_kernel<128><<<512, 256, 0, stream>>>(y3, gsum3, gsq3);
  finalize_kernel<<<1, 128, 0, stream>>>(gsum3, gsq3, g3, be3, scale3, shift3, 128);
  maxpool_kernel<<<BATCH*(SPTS/16), 256, 0, stream>>>(y3, scale3, shift3, out1);
}

// Round 5
// 2641.848 us; speedup vs baseline: 1.0662x; 1.0662x over previous
//
#include <hip/hip_runtime.h>
#include <hip/hip_bf16.h>
#include <stdint.h>

#define BATCH 8
#define NPTS  16384
#define DIMF  64
#define SPTS  1024
#define NSAMP 32
#define MTOT  (BATCH*SPTS*NSAMP)   // 262144

__device__ __forceinline__ float bfu_lo(uint32_t u){ return __uint_as_float(u<<16); }
__device__ __forceinline__ float bfu_hi(uint32_t u){ return __uint_as_float(u & 0xffff0000u); }
__device__ __forceinline__ uint16_t f2bf(float f){
  __hip_bfloat16 h = __float2bfloat16(f);
  uint16_t u; __builtin_memcpy(&u, &h, 2); return u;
}

// ---------------- prep: transpose points (B,64,N)->(B,N,64) ----------------
__global__ __launch_bounds__(256) void transpose_kernel(const float* __restrict__ pts,
                                                        float* __restrict__ ptsT){
  __shared__ float tile[32][33];
  int b = blockIdx.z;
  int n0 = blockIdx.x*32, c0 = blockIdx.y*32;
  int tx = threadIdx.x & 31, ty = threadIdx.x >> 5;
  const float* src = pts + (size_t)b*DIMF*NPTS;
  float* dst = ptsT + (size_t)b*NPTS*DIMF;
#pragma unroll
  for (int j=0;j<4;j++)
    tile[ty+8*j][tx] = src[(size_t)(c0+ty+8*j)*NPTS + n0 + tx];
  __syncthreads();
#pragma unroll
  for (int j=0;j<4;j++)
    dst[(size_t)(n0+ty+8*j)*DIMF + c0 + tx] = tile[tx][ty+8*j];
}

// ---------------- FPS: 1 block (512 thr) per batch, bit-exact f32 ----------------
// One barrier per iteration: per-wave (best,idx) -> parity-double-buffered LDS,
// barrier, then every wave redundantly reduces the 8 wave-results in-register.
__global__ __launch_bounds__(512, 2) void fps_kernel(const float* __restrict__ xyz,
                                                     float* __restrict__ out0){
  int b = blockIdx.x;
  const float* X = xyz + (size_t)b*3*NPTS;
  int t = threadIdx.x;
  int lane = t & 63, wid = t >> 6;   // 8 waves
  float px[32], py[32], pz[32], dst[32];
#pragma unroll
  for (int k=0;k<32;k++){
    int n = t + (k<<9);
    px[k]=X[n]; py[k]=X[NPTS+n]; pz[k]=X[2*NPTS+n];
    dst[k]=1e10f;
  }
  __shared__ float rv[2][8];
  __shared__ int   ri[2][8];
  int far = 0;
  float* o = out0 + (size_t)b*3*SPTS;
  for (int s=0;s<SPTS;s++){
    float cx = X[far], cy = X[NPTS+far], cz = X[2*NPTS+far];
    if (t==0){ o[s]=cx; o[SPTS+s]=cy; o[2*SPTS+s]=cz; }
    if (s==SPTS-1) break;
    float best = -1.0f; int bi = 0x7fffffff;
#pragma unroll
    for (int k=0;k<32;k++){
      float dx=__fsub_rn(px[k],cx), dy=__fsub_rn(py[k],cy), dz=__fsub_rn(pz[k],cz);
      float d = __fadd_rn(__fadd_rn(__fmul_rn(dx,dx),__fmul_rn(dy,dy)),__fmul_rn(dz,dz));
      d = fminf(dst[k], d); dst[k] = d;
      if (d > best){ best = d; bi = t + (k<<9); }   // ascending n in k -> first-max
    }
#pragma unroll
    for (int off=1; off<64; off<<=1){
      float ov = __shfl_xor(best, off);
      int   oi = __shfl_xor(bi, off);
      if (ov > best || (ov == best && oi < bi)){ best = ov; bi = oi; }
    }
    int p = s & 1;
    if (lane==0){ rv[p][wid]=best; ri[p][wid]=bi; }
    __syncthreads();
    float v = rv[p][lane&7]; int j = ri[p][lane&7];
#pragma unroll
    for (int off=1; off<8; off<<=1){
      float ov = __shfl_xor(v, off);
      int   oj = __shfl_xor(j, off);
      if (ov > v || (ov == v && oj < j)){ v = ov; j = oj; }
    }
    far = j;   // identical in every lane/wave
  }
}

// ---------------- ball query: XLA-CPU f32 replication ----------------
// A (query norm), B (point norm): plain sequential ((x^2+y^2)+z^2)  [XLA reduce, no FMA]
// C (dot): Eigen gemm FMA chain fma(z*nz, fma(y*ny, x*nx))          [einsum -> Eigen]
// sqr = (A+B) - 2*C  (x2 exact, fuse-independent)
__global__ __launch_bounds__(256) void ball_kernel(const float* __restrict__ xyz,
                                                   const float* __restrict__ newxyz,
                                                   int* __restrict__ idxo){
  int b  = blockIdx.x >> 5;
  int sc = blockIdx.x & 31;           // 32 s per block
  const float* X  = xyz + (size_t)b*3*NPTS;
  int t = threadIdx.x, lane = t & 63, w = t >> 6;
  __shared__ float lx[512], ly[512], lz[512], ls[512];
  __shared__ int done;
  if (t==0) done = 0;
  const float rsq = 0.01f;
  float nx[8], ny[8], nz[8], sn[8];
  int cnt[8], first[8];
  int sbase = sc*32 + w*8;
#pragma unroll
  for (int q=0;q<8;q++){
    int s = sbase + q;
    nx[q] = newxyz[(size_t)b*3*SPTS + s];
    ny[q] = newxyz[(size_t)b*3*SPTS + SPTS + s];
    nz[q] = newxyz[(size_t)b*3*SPTS + 2*SPTS + s];
    sn[q] = __fadd_rn(__fadd_rn(__fmul_rn(nx[q],nx[q]),__fmul_rn(ny[q],ny[q])),
                      __fmul_rn(nz[q],nz[q]));
    cnt[q]=0; first[q]=0;
  }
  __syncthreads();
  for (int T=0;T<32;T++){
    {
      float ax = X[T*512 + t], ay = X[NPTS + T*512 + t], az = X[2*NPTS + T*512 + t];
      lx[t]=ax; ly[t]=ay; lz[t]=az;
      ls[t] = __fadd_rn(__fadd_rn(__fmul_rn(ax,ax),__fmul_rn(ay,ay)),__fmul_rn(az,az));
      float bx = X[T*512 + t + 256], by = X[NPTS + T*512 + t + 256], bz = X[2*NPTS + T*512 + t + 256];
      lx[t+256]=bx; ly[t+256]=by; lz[t+256]=bz;
      ls[t+256] = __fadd_rn(__fadd_rn(__fmul_rn(bx,bx),__fmul_rn(by,by)),__fmul_rn(bz,bz));
    }
    __syncthreads();
#pragma unroll
    for (int q=0;q<8;q++){
      if (cnt[q] >= NSAMP) continue;
      int s = sbase + q;
      int* op = idxo + ((size_t)(b*SPTS + s))*NSAMP;
      for (int c=0;c<8;c++){
        int li = c*64 + lane;
        float dot = fmaf(nz[q], lz[li], fmaf(ny[q], ly[li], __fmul_rn(nx[q], lx[li])));
        float sq  = __fsub_rn(__fadd_rn(sn[q], ls[li]), __fmul_rn(2.0f, dot));
        bool in = (sq <= rsq);
        unsigned long long m = __ballot(in);
        if (cnt[q]==0 && m) first[q] = T*512 + c*64 + (int)__builtin_ctzll(m);
        if (in){
          int slot = cnt[q] + (int)__popcll(m & ((1ull<<lane)-1ull));
          if (slot < NSAMP) op[slot] = T*512 + li;
        }
        cnt[q] += (int)__popcll(m);
        if (cnt[q] >= NSAMP){ if (lane==0) atomicAdd(&done,1); break; }
      }
    }
    __syncthreads();
    if (done >= 32) break;   // uniform across the block
  }
#pragma unroll
  for (int q=0;q<8;q++){
    if (cnt[q] < NSAMP){
      int s = sbase + q;
      int* op = idxo + ((size_t)(b*SPTS + s))*NSAMP;
      if (lane >= cnt[q] && lane < NSAMP) op[lane] = first[q];
    }
  }
}

// ---------------- GEMM1: fused gather (xyz diff + pts) x w1 -> y1 (bf16) ----------------
__global__ __launch_bounds__(256) void gemm1_kernel(const float* __restrict__ xyz,
                                                    const float* __restrict__ ptsT,
                                                    const int* __restrict__ idx,
                                                    const float* __restrict__ newxyz,
                                                    const float* __restrict__ w1,
                                                    const float* __restrict__ b1,
                                                    uint16_t* __restrict__ y1){
  __shared__ float As[128*69];
  __shared__ float Ws[67*64];
  __shared__ float bias[64];
  __shared__ int   ndx[128];
  __shared__ float nxs[4][3];
  int t = threadIdx.x;
  int g0 = blockIdx.x*128;
  if (t < 128) ndx[t] = idx[g0 + t];
  if (t < 12){
    int grp = t/3, c = t%3;
    int bs = (g0>>5) + grp; int b = bs>>10, s = bs & 1023;
    nxs[grp][c] = newxyz[(size_t)b*3*SPTS + c*SPTS + s];
  }
  if (t < 64) bias[t] = b1[t];
  for (int e=t; e<67*64; e+=256){ int k=e>>6, c=e&63; Ws[k*64+c] = w1[c*67+k]; }
  __syncthreads();
  {
    int r = t>>1, h = t&1;
    int n = ndx[r];
    int bs = (g0>>5) + (r>>5); int b = bs>>10;
    const float* pr = ptsT + ((size_t)(b*NPTS + n))*64 + h*32;
    float* ar = As + r*69;
    if (h==0){
      int grp = r>>5;
      ar[0] = __fsub_rn(xyz[(size_t)b*3*NPTS + n],          nxs[grp][0]);
      ar[1] = __fsub_rn(xyz[(size_t)b*3*NPTS + NPTS + n],   nxs[grp][1]);
      ar[2] = __fsub_rn(xyz[(size_t)b*3*NPTS + 2*NPTS + n], nxs[grp][2]);
    }
    float* ap = ar + 3 + h*32;
#pragma unroll
    for (int j=0;j<8;j++){
      float4 v = *(const float4*)(pr + j*4);
      ap[j*4+0]=v.x; ap[j*4+1]=v.y; ap[j*4+2]=v.z; ap[j*4+3]=v.w;
    }
  }
  __syncthreads();
  int rg = t>>3, cg = t&7;
  float acc[4][8];
#pragma unroll
  for (int i=0;i<4;i++)
#pragma unroll
    for (int j=0;j<8;j++) acc[i][j]=0.f;
  for (int k=0;k<67;k++){
    float a0 = As[(rg*4+0)*69+k];
    float a1 = As[(rg*4+1)*69+k];
    float a2 = As[(rg*4+2)*69+k];
    float a3 = As[(rg*4+3)*69+k];
    const float* wr = Ws + k*64 + cg*8;
    float4 w0 = *(const float4*)wr;
    float4 w1v = *(const float4*)(wr+4);
    float wj[8] = {w0.x,w0.y,w0.z,w0.w,w1v.x,w1v.y,w1v.z,w1v.w};
#pragma unroll
    for (int j=0;j<8;j++){
      acc[0][j] = fmaf(a0, wj[j], acc[0][j]);
      acc[1][j] = fmaf(a1, wj[j], acc[1][j]);
      acc[2][j] = fmaf(a2, wj[j], acc[2][j]);
      acc[3][j] = fmaf(a3, wj[j], acc[3][j]);
    }
  }
#pragma unroll
  for (int i=0;i<4;i++){
    int gr = g0 + rg*4 + i;
    uint16_t* yr = y1 + (size_t)gr*64 + cg*8;
    uint4 vv;
    uint32_t u[4];
#pragma unroll
    for (int j=0;j<4;j++){
      float v0 = acc[i][2*j]   + bias[cg*8+2*j];
      float v1 = acc[i][2*j+1] + bias[cg*8+2*j+1];
      u[j] = (uint32_t)f2bf(v0) | ((uint32_t)f2bf(v1)<<16);
    }
    vv.x=u[0]; vv.y=u[1]; vv.z=u[2]; vv.w=u[3];
    *(uint4*)yr = vv;
  }
}

// ---------------- GEMM2: relu(bn(y1)) x w2 -> y2 (bf16), K=64 ----------------
__global__ __launch_bounds__(256) void gemm2_kernel(const uint16_t* __restrict__ yin,
                                                    const float* __restrict__ w2,
                                                    const float* __restrict__ b2,
                                                    const float* __restrict__ scale,
                                                    const float* __restrict__ shift,
                                                    uint16_t* __restrict__ yout){
  __shared__ float As[128*65];
  __shared__ float Ws[64*64];
  __shared__ float bias[64], sc[64], sh[64];
  int t = threadIdx.x;
  int g0 = blockIdx.x*128;
  if (t < 64){ bias[t]=b2[t]; sc[t]=scale[t]; sh[t]=shift[t]; }
  for (int e=t; e<64*64; e+=256){ int k=e>>6, c=e&63; Ws[k*64+c] = w2[c*64+k]; }
  __syncthreads();
  {
    int r = t>>1, h = t&1;
    const uint4* yv = (const uint4*)(yin + (size_t)(g0+r)*64 + h*32);
    float* ar = As + r*65 + h*32;
#pragma unroll
    for (int j=0;j<4;j++){
      uint4 u = yv[j];
      uint32_t vv[4] = {u.x,u.y,u.z,u.w};
#pragma unroll
      for (int m=0;m<4;m++){
        int c = h*32 + j*8 + m*2;
        ar[j*8+m*2]   = fmaxf(fmaf(bfu_lo(vv[m]), sc[c],   sh[c]),   0.f);
        ar[j*8+m*2+1] = fmaxf(fmaf(bfu_hi(vv[m]), sc[c+1], sh[c+1]), 0.f);
      }
    }
  }
  __syncthreads();
  int rg = t>>3, cg = t&7;
  float acc[4][8];
#pragma unroll
  for (int i=0;i<4;i++)
#pragma unroll
    for (int j=0;j<8;j++) acc[i][j]=0.f;
  for (int k=0;k<64;k++){
    float a0 = As[(rg*4+0)*65+k];
    float a1 = As[(rg*4+1)*65+k];
    float a2 = As[(rg*4+2)*65+k];
    float a3 = As[(rg*4+3)*65+k];
    const float* wr = Ws + k*64 + cg*8;
    float4 w0 = *(const float4*)wr;
    float4 w1v = *(const float4*)(wr+4);
    float wj[8] = {w0.x,w0.y,w0.z,w0.w,w1v.x,w1v.y,w1v.z,w1v.w};
#pragma unroll
    for (int j=0;j<8;j++){
      acc[0][j] = fmaf(a0, wj[j], acc[0][j]);
      acc[1][j] = fmaf(a1, wj[j], acc[1][j]);
      acc[2][j] = fmaf(a2, wj[j], acc[2][j]);
      acc[3][j] = fmaf(a3, wj[j], acc[3][j]);
    }
  }
#pragma unroll
  for (int i=0;i<4;i++){
    int gr = g0 + rg*4 + i;
    uint16_t* yr = yout + (size_t)gr*64 + cg*8;
    uint4 vv; uint32_t u[4];
#pragma unroll
    for (int j=0;j<4;j++){
      float v0 = acc[i][2*j]   + bias[cg*8+2*j];
      float v1 = acc[i][2*j+1] + bias[cg*8+2*j+1];
      u[j] = (uint32_t)f2bf(v0) | ((uint32_t)f2bf(v1)<<16);
    }
    vv.x=u[0]; vv.y=u[1]; vv.z=u[2]; vv.w=u[3];
    *(uint4*)yr = vv;
  }
}

// ---------------- GEMM3: relu(bn(y2)) x w3 -> y3 (bf16), K=64, OUT=128 ----------------
__global__ __launch_bounds__(256) void gemm3_kernel(const uint16_t* __restrict__ yin,
                                                    const float* __restrict__ w3,
                                                    const float* __restrict__ b3,
                                                    const float* __restrict__ scale,
                                                    const float* __restrict__ shift,
                                                    uint16_t* __restrict__ yout){
  __shared__ float As[64*65];
  __shared__ float Ws[64*128];
  __shared__ float bias[128], sc[64], sh[64];
  int t = threadIdx.x;
  int g0 = blockIdx.x*64;
  if (t < 128) bias[t]=b3[t];
  if (t < 64){ sc[t]=scale[t]; sh[t]=shift[t]; }
  for (int e=t; e<64*128; e+=256){ int k=e>>7, c=e&127; Ws[k*128+c] = w3[c*64+k]; }
  __syncthreads();
  {
    int r = t>>2, h = t&3;
    const uint4* yv = (const uint4*)(yin + (size_t)(g0+r)*64 + h*16);
    float* ar = As + r*65 + h*16;
#pragma unroll
    for (int j=0;j<2;j++){
      uint4 u = yv[j];
      uint32_t vv[4] = {u.x,u.y,u.z,u.w};
#pragma unroll
      for (int m=0;m<4;m++){
        int c = h*16 + j*8 + m*2;
        ar[j*8+m*2]   = fmaxf(fmaf(bfu_lo(vv[m]), sc[c],   sh[c]),   0.f);
        ar[j*8+m*2+1] = fmaxf(fmaf(bfu_hi(vv[m]), sc[c+1], sh[c+1]), 0.f);
      }
    }
  }
  __syncthreads();
  int rg = t>>4, cg = t&15;
  float acc[4][8];
#pragma unroll
  for (int i=0;i<4;i++)
#pragma unroll
    for (int j=0;j<8;j++) acc[i][j]=0.f;
  for (int k=0;k<64;k++){
    float a0 = As[(rg*4+0)*65+k];
    float a1 = As[(rg*4+1)*65+k];
    float a2 = As[(rg*4+2)*65+k];
    float a3 = As[(rg*4+3)*65+k];
    const float* wr = Ws + k*128 + cg*8;
    float4 w0 = *(const float4*)wr;
    float4 w1v = *(const float4*)(wr+4);
    float wj[8] = {w0.x,w0.y,w0.z,w0.w,w1v.x,w1v.y,w1v.z,w1v.w};
#pragma unroll
    for (int j=0;j<8;j++){
      acc[0][j] = fmaf(a0, wj[j], acc[0][j]);
      acc[1][j] = fmaf(a1, wj[j], acc[1][j]);
      acc[2][j] = fmaf(a2, wj[j], acc[2][j]);
      acc[3][j] = fmaf(a3, wj[j], acc[3][j]);
    }
  }
#pragma unroll
  for (int i=0;i<4;i++){
    int gr = g0 + rg*4 + i;
    uint16_t* yr = yout + (size_t)gr*128 + cg*8;
    uint4 vv; uint32_t u[4];
#pragma unroll
    for (int j=0;j<4;j++){
      float v0 = acc[i][2*j]   + bias[cg*8+2*j];
      float v1 = acc[i][2*j+1] + bias[cg*8+2*j+1];
      u[j] = (uint32_t)f2bf(v0) | ((uint32_t)f2bf(v1)<<16);
    }
    vv.x=u[0]; vv.y=u[1]; vv.z=u[2]; vv.w=u[3];
    *(uint4*)yr = vv;
  }
}

// ---------------- per-channel stats (sum, sumsq) ----------------
template<int C>
__global__ __launch_bounds__(256) void stats_kernel(const uint16_t* __restrict__ y,
                                                    float* __restrict__ gsum,
                                                    float* __restrict__ gsq){
  constexpr int CP  = C/2;
  constexpr int RSL = 256/CP;
  int t = threadIdx.x;
  int c0 = t % CP, rs = t / CP;
  float s0=0.f,q0=0.f,s1=0.f,q1=0.f;
#pragma unroll 4
  for (int i=0;i<512/RSL;i++){
    int r = blockIdx.x*512 + rs + i*RSL;
    uint32_t u = *(const uint32_t*)(y + (size_t)r*C + 2*c0);
    float v0 = bfu_lo(u), v1 = bfu_hi(u);
    s0 += v0; q0 += v0*v0; s1 += v1; q1 += v1*v1;
  }
  __shared__ float red[4][256];
  red[0][t]=s0; red[1][t]=q0; red[2][t]=s1; red[3][t]=q1;
  __syncthreads();
  if (t < CP){
    float a0=0,a1=0,a2=0,a3=0;
    for (int k=0;k<RSL;k++){
      a0+=red[0][k*CP+t]; a1+=red[1][k*CP+t]; a2+=red[2][k*CP+t]; a3+=red[3][k*CP+t];
    }
    atomicAdd(&gsum[2*t],   a0); atomicAdd(&gsq[2*t],   a1);
    atomicAdd(&gsum[2*t+1], a2); atomicAdd(&gsq[2*t+1], a3);
  }
}

__global__ void finalize_kernel(const float* __restrict__ gsum, const float* __restrict__ gsq,
                                const float* __restrict__ g, const float* __restrict__ be,
                                float* __restrict__ scale, float* __restrict__ shift, int C){
  int c = threadIdx.x;
  if (c >= C) return;
  double mean = (double)gsum[c] / (double)MTOT;
  double var  = (double)gsq[c] / (double)MTOT - mean*mean;
  double s    = (double)g[c] / sqrt(var + 1e-5);
  scale[c] = (float)s;
  shift[c] = (float)((double)be[c] - mean*s);
}

// ---------------- bn3 + relu + maxpool over nsample + transpose ----------------
__global__ __launch_bounds__(256) void maxpool_kernel(const uint16_t* __restrict__ y3,
                                                      const float* __restrict__ scale,
                                                      const float* __restrict__ shift,
                                                      float* __restrict__ out1){
  __shared__ float tr[16][129];
  int t = threadIdx.x;
  int b = blockIdx.x >> 6;
  int s0 = (blockIdx.x & 63) * 16;
  int ch = t & 127, sl0 = t >> 7;
  float scv = scale[ch], shv = shift[ch];
  for (int sl=sl0; sl<16; sl+=2){
    int bs = b*SPTS + s0 + sl;
    const uint16_t* yr = y3 + (size_t)bs*NSAMP*128 + ch;
    float m = 0.0f;
#pragma unroll 4
    for (int k=0;k<NSAMP;k++){
      float v = __uint_as_float(((uint32_t)yr[k*128])<<16);
      float z = fmaxf(fmaf(v, scv, shv), 0.f);
      m = fmaxf(m, z);
    }
    tr[sl][ch] = m;
  }
  __syncthreads();
  int ch2 = t >> 1, hh = t & 1;
  float vals[8];
#pragma unroll
  for (int i=0;i<8;i++) vals[i] = tr[hh*8+i][ch2];
  float* op = out1 + (size_t)b*131072 + (size_t)ch2*1024 + s0 + hh*8;
  float4 v0; v0.x=vals[0]; v0.y=vals[1]; v0.z=vals[2]; v0.w=vals[3];
  float4 v1; v1.x=vals[4]; v1.y=vals[5]; v1.z=vals[6]; v1.w=vals[7];
  *(float4*)op = v0;
  *(float4*)(op+4) = v1;
}

extern "C" void kernel_launch(void* const* d_in, const int* in_sizes, int n_in,
                              void* d_out, int out_size, void* d_ws, size_t ws_size,
                              hipStream_t stream){
  (void)in_sizes; (void)n_in; (void)out_size; (void)ws_size;
  const float* xyz = (const float*)d_in[0];
  const float* pts = (const float*)d_in[1];
  const float* w1 = (const float*)d_in[2];  const float* b1 = (const float*)d_in[3];
  const float* g1 = (const float*)d_in[4];  const float* be1 = (const float*)d_in[5];
  const float* w2 = (const float*)d_in[6];  const float* b2 = (const float*)d_in[7];
  const float* g2 = (const float*)d_in[8];  const float* be2 = (const float*)d_in[9];
  const float* w3 = (const float*)d_in[10]; const float* b3 = (const float*)d_in[11];
  const float* g3 = (const float*)d_in[12]; const float* be3 = (const float*)d_in[13];

  float* out0 = (float*)d_out;                 // (B,3,1024)
  float* out1 = out0 + BATCH*3*SPTS;           // (B,128,1024)

  char* ws = (char*)d_ws;
  float*    ptsT = (float*)(ws + 0);                       // 33,554,432 B
  int*      idx  = (int*)  (ws + 34078720);                //  1,048,576 B
  uint16_t* y1   = (uint16_t*)(ws + 35127296);             // 33,554,432 B
  uint16_t* y2   = (uint16_t*)(ws + 68681728);             // 33,554,432 B
  uint16_t* y3   = (uint16_t*)(ws + 102236160);            // 67,108,864 B
  float*    stats = (float*)(ws + 169345024);              // 1536 floats
  float* gsum1 = stats;        float* gsq1 = stats + 128;
  float* gsum2 = stats + 256;  float* gsq2 = stats + 384;
  float* gsum3 = stats + 512;  float* gsq3 = stats + 640;
  float* scale1 = stats + 768; float* shift1 = stats + 896;
  float* scale2 = stats + 1024; float* shift2 = stats + 1152;
  float* scale3 = stats + 1280; float* shift3 = stats + 1408;

  hipMemsetAsync(stats, 0, 768*sizeof(float), stream);

  transpose_kernel<<<dim3(NPTS/32, DIMF/32, BATCH), 256, 0, stream>>>(pts, ptsT);
  fps_kernel<<<BATCH, 512, 0, stream>>>(xyz, out0);
  ball_kernel<<<BATCH*32, 256, 0, stream>>>(xyz, out0, idx);
  gemm1_kernel<<<MTOT/128, 256, 0, stream>>>(xyz, ptsT, idx, out0, w1, b1, y1);
  stats_kernel<64><<<512, 256, 0, stream>>>(y1, gsum1, gsq1);
  finalize_kernel<<<1, 128, 0, stream>>>(gsum1, gsq1, g1, be1, scale1, shift1, 64);
  gemm2_kernel<<<MTOT/128, 256, 0, stream>>>(y1, w2, b2, scale1, shift1, y2);
  stats_kernel<64><<<512, 256, 0, stream>>>(y2, gsum2, gsq2);
  finalize_kernel<<<1, 128, 0, stream>>>(gsum2, gsq2, g2, be2, scale2, shift2, 64);
  gemm3_kernel<<<MTOT/64, 256, 0, stream>>>(y2, w3, b3, scale2, shift2, y3);
  stats_kernel<128><<<512, 256, 0, stream>>>(y3, gsum3, gsq3);
  finalize_kernel<<<1, 128, 0, stream>>>(gsum3, gsq3, g3, be3, scale3, shift3, 128);
  maxpool_kernel<<<BATCH*(SPTS/16), 256, 0, stream>>>(y3, scale3, shift3, out1);
}

// Round 6
// 2633.402 us; speedup vs baseline: 1.0696x; 1.0032x over previous
//
#include <hip/hip_runtime.h>
#include <hip/hip_bf16.h>
#include <stdint.h>

#define BATCH 8
#define NPTS  16384
#define DIMF  64
#define SPTS  1024
#define NSAMP 32
#define MTOT  (BATCH*SPTS*NSAMP)   // 262144

__device__ __forceinline__ float bfu_lo(uint32_t u){ return __uint_as_float(u<<16); }
__device__ __forceinline__ float bfu_hi(uint32_t u){ return __uint_as_float(u & 0xffff0000u); }
__device__ __forceinline__ uint16_t f2bf(float f){
  __hip_bfloat16 h = __float2bfloat16(f);
  uint16_t u; __builtin_memcpy(&u, &h, 2); return u;
}

// ---------------- prep: transpose points (B,64,N)->(B,N,64) ----------------
__global__ __launch_bounds__(256) void transpose_kernel(const float* __restrict__ pts,
                                                        float* __restrict__ ptsT){
  __shared__ float tile[32][33];
  int b = blockIdx.z;
  int n0 = blockIdx.x*32, c0 = blockIdx.y*32;
  int tx = threadIdx.x & 31, ty = threadIdx.x >> 5;
  const float* src = pts + (size_t)b*DIMF*NPTS;
  float* dst = ptsT + (size_t)b*NPTS*DIMF;
#pragma unroll
  for (int j=0;j<4;j++)
    tile[ty+8*j][tx] = src[(size_t)(c0+ty+8*j)*NPTS + n0 + tx];
  __syncthreads();
#pragma unroll
  for (int j=0;j<4;j++)
    dst[(size_t)(n0+ty+8*j)*DIMF + c0 + tx] = tile[tx][ty+8*j];
}

// ---------------- FPS: 1 block (512 thr) per batch, bit-exact f32 ----------------
// Points pinned in VGPRs via opaque asm (compiler was rematerializing the loads
// every iteration -> ~196KB/iter L2 traffic, the R5 bottleneck). One barrier per
// iteration with parity-double-buffered per-wave results.
__global__ __launch_bounds__(512, 2) void fps_kernel(const float* __restrict__ xyz,
                                                     float* __restrict__ out0){
  int b = blockIdx.x;
  const float* X = xyz + (size_t)b*3*NPTS;
  int t = threadIdx.x;
  int lane = t & 63, wid = t >> 6;   // 8 waves
  float px[32], py[32], pz[32], dst[32];
#pragma unroll
  for (int k=0;k<32;k++){
    int n = t + (k<<9);
    px[k]=X[n]; py[k]=X[NPTS+n]; pz[k]=X[2*NPTS+n];
    dst[k]=1e10f;
  }
  // Pin point coords in registers: opaque asm makes remat-from-memory illegal.
#pragma unroll
  for (int k=0;k<32;k++){
    asm volatile("" : "+v"(px[k]), "+v"(py[k]), "+v"(pz[k]));
  }
  __shared__ float rv[2][8];
  __shared__ int   ri[2][8];
  int far = 0;
  float* o = out0 + (size_t)b*3*SPTS;
  for (int s=0;s<SPTS;s++){
    float cx = X[far], cy = X[NPTS+far], cz = X[2*NPTS+far];
    if (t==0){ o[s]=cx; o[SPTS+s]=cy; o[2*SPTS+s]=cz; }
    if (s==SPTS-1) break;
    float best = -1.0f; int bi = 0x7fffffff;
#pragma unroll
    for (int k=0;k<32;k++){
      float dx=__fsub_rn(px[k],cx), dy=__fsub_rn(py[k],cy), dz=__fsub_rn(pz[k],cz);
      float d = __fadd_rn(__fadd_rn(__fmul_rn(dx,dx),__fmul_rn(dy,dy)),__fmul_rn(dz,dz));
      d = fminf(dst[k], d); dst[k] = d;
      if (d > best){ best = d; bi = t + (k<<9); }   // ascending n in k -> first-max
    }
#pragma unroll
    for (int off=1; off<64; off<<=1){
      float ov = __shfl_xor(best, off);
      int   oi = __shfl_xor(bi, off);
      if (ov > best || (ov == best && oi < bi)){ best = ov; bi = oi; }
    }
    int p = s & 1;
    if (lane==0){ rv[p][wid]=best; ri[p][wid]=bi; }
    __syncthreads();
    float v = rv[p][lane&7]; int j = ri[p][lane&7];
#pragma unroll
    for (int off=1; off<8; off<<=1){
      float ov = __shfl_xor(v, off);
      int   oj = __shfl_xor(j, off);
      if (ov > v || (ov == v && oj < j)){ v = ov; j = oj; }
    }
    far = __builtin_amdgcn_readfirstlane(j);   // uniform -> scalar loads for centroid
  }
}

// ---------------- ball query: XLA-CPU f32 replication ----------------
// A (query norm), B (point norm): plain sequential ((x^2+y^2)+z^2)  [XLA reduce, no FMA]
// C (dot): Eigen gemm FMA chain fma(z*nz, fma(y*ny, x*nx))          [einsum -> Eigen]
// sqr = (A+B) - 2*C  (x2 exact, fuse-independent)
__global__ __launch_bounds__(256) void ball_kernel(const float* __restrict__ xyz,
                                                   const float* __restrict__ newxyz,
                                                   int* __restrict__ idxo){
  int b  = blockIdx.x >> 5;
  int sc = blockIdx.x & 31;           // 32 s per block
  const float* X  = xyz + (size_t)b*3*NPTS;
  int t = threadIdx.x, lane = t & 63, w = t >> 6;
  __shared__ float lx[512], ly[512], lz[512], ls[512];
  __shared__ int done;
  if (t==0) done = 0;
  const float rsq = 0.01f;
  float nx[8], ny[8], nz[8], sn[8];
  int cnt[8], first[8];
  int sbase = sc*32 + w*8;
#pragma unroll
  for (int q=0;q<8;q++){
    int s = sbase + q;
    nx[q] = newxyz[(size_t)b*3*SPTS + s];
    ny[q] = newxyz[(size_t)b*3*SPTS + SPTS + s];
    nz[q] = newxyz[(size_t)b*3*SPTS + 2*SPTS + s];
    sn[q] = __fadd_rn(__fadd_rn(__fmul_rn(nx[q],nx[q]),__fmul_rn(ny[q],ny[q])),
                      __fmul_rn(nz[q],nz[q]));
    cnt[q]=0; first[q]=0;
  }
  __syncthreads();
  for (int T=0;T<32;T++){
    {
      float ax = X[T*512 + t], ay = X[NPTS + T*512 + t], az = X[2*NPTS + T*512 + t];
      lx[t]=ax; ly[t]=ay; lz[t]=az;
      ls[t] = __fadd_rn(__fadd_rn(__fmul_rn(ax,ax),__fmul_rn(ay,ay)),__fmul_rn(az,az));
      float bx = X[T*512 + t + 256], by = X[NPTS + T*512 + t + 256], bz = X[2*NPTS + T*512 + t + 256];
      lx[t+256]=bx; ly[t+256]=by; lz[t+256]=bz;
      ls[t+256] = __fadd_rn(__fadd_rn(__fmul_rn(bx,bx),__fmul_rn(by,by)),__fmul_rn(bz,bz));
    }
    __syncthreads();
#pragma unroll
    for (int q=0;q<8;q++){
      if (cnt[q] >= NSAMP) continue;
      int s = sbase + q;
      int* op = idxo + ((size_t)(b*SPTS + s))*NSAMP;
      for (int c=0;c<8;c++){
        int li = c*64 + lane;
        float dot = fmaf(nz[q], lz[li], fmaf(ny[q], ly[li], __fmul_rn(nx[q], lx[li])));
        float sq  = __fsub_rn(__fadd_rn(sn[q], ls[li]), __fmul_rn(2.0f, dot));
        bool in = (sq <= rsq);
        unsigned long long m = __ballot(in);
        if (cnt[q]==0 && m) first[q] = T*512 + c*64 + (int)__builtin_ctzll(m);
        if (in){
          int slot = cnt[q] + (int)__popcll(m & ((1ull<<lane)-1ull));
          if (slot < NSAMP) op[slot] = T*512 + li;
        }
        cnt[q] += (int)__popcll(m);
        if (cnt[q] >= NSAMP){ if (lane==0) atomicAdd(&done,1); break; }
      }
    }
    __syncthreads();
    if (done >= 32) break;   // uniform across the block
  }
#pragma unroll
  for (int q=0;q<8;q++){
    if (cnt[q] < NSAMP){
      int s = sbase + q;
      int* op = idxo + ((size_t)(b*SPTS + s))*NSAMP;
      if (lane >= cnt[q] && lane < NSAMP) op[lane] = first[q];
    }
  }
}

// ---------------- GEMM1: fused gather (xyz diff + pts) x w1 -> y1 (bf16) ----------------
__global__ __launch_bounds__(256) void gemm1_kernel(const float* __restrict__ xyz,
                                                    const float* __restrict__ ptsT,
                                                    const int* __restrict__ idx,
                                                    const float* __restrict__ newxyz,
                                                    const float* __restrict__ w1,
                                                    const float* __restrict__ b1,
                                                    uint16_t* __restrict__ y1){
  __shared__ float As[128*69];
  __shared__ float Ws[67*64];
  __shared__ float bias[64];
  __shared__ int   ndx[128];
  __shared__ float nxs[4][3];
  int t = threadIdx.x;
  int g0 = blockIdx.x*128;
  if (t < 128) ndx[t] = idx[g0 + t];
  if (t < 12){
    int grp = t/3, c = t%3;
    int bs = (g0>>5) + grp; int b = bs>>10, s = bs & 1023;
    nxs[grp][c] = newxyz[(size_t)b*3*SPTS + c*SPTS + s];
  }
  if (t < 64) bias[t] = b1[t];
  for (int e=t; e<67*64; e+=256){ int k=e>>6, c=e&63; Ws[k*64+c] = w1[c*67+k]; }
  __syncthreads();
  {
    int r = t>>1, h = t&1;
    int n = ndx[r];
    int bs = (g0>>5) + (r>>5); int b = bs>>10;
    const float* pr = ptsT + ((size_t)(b*NPTS + n))*64 + h*32;
    float* ar = As + r*69;
    if (h==0){
      int grp = r>>5;
      ar[0] = __fsub_rn(xyz[(size_t)b*3*NPTS + n],          nxs[grp][0]);
      ar[1] = __fsub_rn(xyz[(size_t)b*3*NPTS + NPTS + n],   nxs[grp][1]);
      ar[2] = __fsub_rn(xyz[(size_t)b*3*NPTS + 2*NPTS + n], nxs[grp][2]);
    }
    float* ap = ar + 3 + h*32;
#pragma unroll
    for (int j=0;j<8;j++){
      float4 v = *(const float4*)(pr + j*4);
      ap[j*4+0]=v.x; ap[j*4+1]=v.y; ap[j*4+2]=v.z; ap[j*4+3]=v.w;
    }
  }
  __syncthreads();
  int rg = t>>3, cg = t&7;
  float acc[4][8];
#pragma unroll
  for (int i=0;i<4;i++)
#pragma unroll
    for (int j=0;j<8;j++) acc[i][j]=0.f;
  for (int k=0;k<67;k++){
    float a0 = As[(rg*4+0)*69+k];
    float a1 = As[(rg*4+1)*69+k];
    float a2 = As[(rg*4+2)*69+k];
    float a3 = As[(rg*4+3)*69+k];
    const float* wr = Ws + k*64 + cg*8;
    float4 w0 = *(const float4*)wr;
    float4 w1v = *(const float4*)(wr+4);
    float wj[8] = {w0.x,w0.y,w0.z,w0.w,w1v.x,w1v.y,w1v.z,w1v.w};
#pragma unroll
    for (int j=0;j<8;j++){
      acc[0][j] = fmaf(a0, wj[j], acc[0][j]);
      acc[1][j] = fmaf(a1, wj[j], acc[1][j]);
      acc[2][j] = fmaf(a2, wj[j], acc[2][j]);
      acc[3][j] = fmaf(a3, wj[j], acc[3][j]);
    }
  }
#pragma unroll
  for (int i=0;i<4;i++){
    int gr = g0 + rg*4 + i;
    uint16_t* yr = y1 + (size_t)gr*64 + cg*8;
    uint4 vv;
    uint32_t u[4];
#pragma unroll
    for (int j=0;j<4;j++){
      float v0 = acc[i][2*j]   + bias[cg*8+2*j];
      float v1 = acc[i][2*j+1] + bias[cg*8+2*j+1];
      u[j] = (uint32_t)f2bf(v0) | ((uint32_t)f2bf(v1)<<16);
    }
    vv.x=u[0]; vv.y=u[1]; vv.z=u[2]; vv.w=u[3];
    *(uint4*)yr = vv;
  }
}

// ---------------- GEMM2: relu(bn(y1)) x w2 -> y2 (bf16), K=64 ----------------
__global__ __launch_bounds__(256) void gemm2_kernel(const uint16_t* __restrict__ yin,
                                                    const float* __restrict__ w2,
                                                    const float* __restrict__ b2,
                                                    const float* __restrict__ scale,
                                                    const float* __restrict__ shift,
                                                    uint16_t* __restrict__ yout){
  __shared__ float As[128*65];
  __shared__ float Ws[64*64];
  __shared__ float bias[64], sc[64], sh[64];
  int t = threadIdx.x;
  int g0 = blockIdx.x*128;
  if (t < 64){ bias[t]=b2[t]; sc[t]=scale[t]; sh[t]=shift[t]; }
  for (int e=t; e<64*64; e+=256){ int k=e>>6, c=e&63; Ws[k*64+c] = w2[c*64+k]; }
  __syncthreads();
  {
    int r = t>>1, h = t&1;
    const uint4* yv = (const uint4*)(yin + (size_t)(g0+r)*64 + h*32);
    float* ar = As + r*65 + h*32;
#pragma unroll
    for (int j=0;j<4;j++){
      uint4 u = yv[j];
      uint32_t vv[4] = {u.x,u.y,u.z,u.w};
#pragma unroll
      for (int m=0;m<4;m++){
        int c = h*32 + j*8 + m*2;
        ar[j*8+m*2]   = fmaxf(fmaf(bfu_lo(vv[m]), sc[c],   sh[c]),   0.f);
        ar[j*8+m*2+1] = fmaxf(fmaf(bfu_hi(vv[m]), sc[c+1], sh[c+1]), 0.f);
      }
    }
  }
  __syncthreads();
  int rg = t>>3, cg = t&7;
  float acc[4][8];
#pragma unroll
  for (int i=0;i<4;i++)
#pragma unroll
    for (int j=0;j<8;j++) acc[i][j]=0.f;
  for (int k=0;k<64;k++){
    float a0 = As[(rg*4+0)*65+k];
    float a1 = As[(rg*4+1)*65+k];
    float a2 = As[(rg*4+2)*65+k];
    float a3 = As[(rg*4+3)*65+k];
    const float* wr = Ws + k*64 + cg*8;
    float4 w0 = *(const float4*)wr;
    float4 w1v = *(const float4*)(wr+4);
    float wj[8] = {w0.x,w0.y,w0.z,w0.w,w1v.x,w1v.y,w1v.z,w1v.w};
#pragma unroll
    for (int j=0;j<8;j++){
      acc[0][j] = fmaf(a0, wj[j], acc[0][j]);
      acc[1][j] = fmaf(a1, wj[j], acc[1][j]);
      acc[2][j] = fmaf(a2, wj[j], acc[2][j]);
      acc[3][j] = fmaf(a3, wj[j], acc[3][j]);
    }
  }
#pragma unroll
  for (int i=0;i<4;i++){
    int gr = g0 + rg*4 + i;
    uint16_t* yr = yout + (size_t)gr*64 + cg*8;
    uint4 vv; uint32_t u[4];
#pragma unroll
    for (int j=0;j<4;j++){
      float v0 = acc[i][2*j]   + bias[cg*8+2*j];
      float v1 = acc[i][2*j+1] + bias[cg*8+2*j+1];
      u[j] = (uint32_t)f2bf(v0) | ((uint32_t)f2bf(v1)<<16);
    }
    vv.x=u[0]; vv.y=u[1]; vv.z=u[2]; vv.w=u[3];
    *(uint4*)yr = vv;
  }
}

// ---------------- GEMM3: relu(bn(y2)) x w3 -> y3 (bf16), K=64, OUT=128 ----------------
__global__ __launch_bounds__(256) void gemm3_kernel(const uint16_t* __restrict__ yin,
                                                    const float* __restrict__ w3,
                                                    const float* __restrict__ b3,
                                                    const float* __restrict__ scale,
                                                    const float* __restrict__ shift,
                                                    uint16_t* __restrict__ yout){
  __shared__ float As[64*65];
  __shared__ float Ws[64*128];
  __shared__ float bias[128], sc[64], sh[64];
  int t = threadIdx.x;
  int g0 = blockIdx.x*64;
  if (t < 128) bias[t]=b3[t];
  if (t < 64){ sc[t]=scale[t]; sh[t]=shift[t]; }
  for (int e=t; e<64*128; e+=256){ int k=e>>7, c=e&127; Ws[k*128+c] = w3[c*64+k]; }
  __syncthreads();
  {
    int r = t>>2, h = t&3;
    const uint4* yv = (const uint4*)(yin + (size_t)(g0+r)*64 + h*16);
    float* ar = As + r*65 + h*16;
#pragma unroll
    for (int j=0;j<2;j++){
      uint4 u = yv[j];
      uint32_t vv[4] = {u.x,u.y,u.z,u.w};
#pragma unroll
      for (int m=0;m<4;m++){
        int c = h*16 + j*8 + m*2;
        ar[j*8+m*2]   = fmaxf(fmaf(bfu_lo(vv[m]), sc[c],   sh[c]),   0.f);
        ar[j*8+m*2+1] = fmaxf(fmaf(bfu_hi(vv[m]), sc[c+1], sh[c+1]), 0.f);
      }
    }
  }
  __syncthreads();
  int rg = t>>4, cg = t&15;
  float acc[4][8];
#pragma unroll
  for (int i=0;i<4;i++)
#pragma unroll
    for (int j=0;j<8;j++) acc[i][j]=0.f;
  for (int k=0;k<64;k++){
    float a0 = As[(rg*4+0)*65+k];
    float a1 = As[(rg*4+1)*65+k];
    float a2 = As[(rg*4+2)*65+k];
    float a3 = As[(rg*4+3)*65+k];
    const float* wr = Ws + k*128 + cg*8;
    float4 w0 = *(const float4*)wr;
    float4 w1v = *(const float4*)(wr+4);
    float wj[8] = {w0.x,w0.y,w0.z,w0.w,w1v.x,w1v.y,w1v.z,w1v.w};
#pragma unroll
    for (int j=0;j<8;j++){
      acc[0][j] = fmaf(a0, wj[j], acc[0][j]);
      acc[1][j] = fmaf(a1, wj[j], acc[1][j]);
      acc[2][j] = fmaf(a2, wj[j], acc[2][j]);
      acc[3][j] = fmaf(a3, wj[j], acc[3][j]);
    }
  }
#pragma unroll
  for (int i=0;i<4;i++){
    int gr = g0 + rg*4 + i;
    uint16_t* yr = yout + (size_t)gr*128 + cg*8;
    uint4 vv; uint32_t u[4];
#pragma unroll
    for (int j=0;j<4;j++){
      float v0 = acc[i][2*j]   + bias[cg*8+2*j];
      float v1 = acc[i][2*j+1] + bias[cg*8+2*j+1];
      u[j] = (uint32_t)f2bf(v0) | ((uint32_t)f2bf(v1)<<16);
    }
    vv.x=u[0]; vv.y=u[1]; vv.z=u[2]; vv.w=u[3];
    *(uint4*)yr = vv;
  }
}

// ---------------- per-channel stats (sum, sumsq) ----------------
template<int C>
__global__ __launch_bounds__(256) void stats_kernel(const uint16_t* __restrict__ y,
                                                    float* __restrict__ gsum,
                                                    float* __restrict__ gsq){
  constexpr int CP  = C/2;
  constexpr int RSL = 256/CP;
  int t = threadIdx.x;
  int c0 = t % CP, rs = t / CP;
  float s0=0.f,q0=0.f,s1=0.f,q1=0.f;
#pragma unroll 4
  for (int i=0;i<512/RSL;i++){
    int r = blockIdx.x*512 + rs + i*RSL;
    uint32_t u = *(const uint32_t*)(y + (size_t)r*C + 2*c0);
    float v0 = bfu_lo(u), v1 = bfu_hi(u);
    s0 += v0; q0 += v0*v0; s1 += v1; q1 += v1*v1;
  }
  __shared__ float red[4][256];
  red[0][t]=s0; red[1][t]=q0; red[2][t]=s1; red[3][t]=q1;
  __syncthreads();
  if (t < CP){
    float a0=0,a1=0,a2=0,a3=0;
    for (int k=0;k<RSL;k++){
      a0+=red[0][k*CP+t]; a1+=red[1][k*CP+t]; a2+=red[2][k*CP+t]; a3+=red[3][k*CP+t];
    }
    atomicAdd(&gsum[2*t],   a0); atomicAdd(&gsq[2*t],   a1);
    atomicAdd(&gsum[2*t+1], a2); atomicAdd(&gsq[2*t+1], a3);
  }
}

__global__ void finalize_kernel(const float* __restrict__ gsum, const float* __restrict__ gsq,
                                const float* __restrict__ g, const float* __restrict__ be,
                                float* __restrict__ scale, float* __restrict__ shift, int C){
  int c = threadIdx.x;
  if (c >= C) return;
  double mean = (double)gsum[c] / (double)MTOT;
  double var  = (double)gsq[c] / (double)MTOT - mean*mean;
  double s    = (double)g[c] / sqrt(var + 1e-5);
  scale[c] = (float)s;
  shift[c] = (float)((double)be[c] - mean*s);
}

// ---------------- bn3 + relu + maxpool over nsample + transpose ----------------
__global__ __launch_bounds__(256) void maxpool_kernel(const uint16_t* __restrict__ y3,
                                                      const float* __restrict__ scale,
                                                      const float* __restrict__ shift,
                                                      float* __restrict__ out1){
  __shared__ float tr[16][129];
  int t = threadIdx.x;
  int b = blockIdx.x >> 6;
  int s0 = (blockIdx.x & 63) * 16;
  int ch = t & 127, sl0 = t >> 7;
  float scv = scale[ch], shv = shift[ch];
  for (int sl=sl0; sl<16; sl+=2){
    int bs = b*SPTS + s0 + sl;
    const uint16_t* yr = y3 + (size_t)bs*NSAMP*128 + ch;
    float m = 0.0f;
#pragma unroll 4
    for (int k=0;k<NSAMP;k++){
      float v = __uint_as_float(((uint32_t)yr[k*128])<<16);
      float z = fmaxf(fmaf(v, scv, shv), 0.f);
      m = fmaxf(m, z);
    }
    tr[sl][ch] = m;
  }
  __syncthreads();
  int ch2 = t >> 1, hh = t & 1;
  float vals[8];
#pragma unroll
  for (int i=0;i<8;i++) vals[i] = tr[hh*8+i][ch2];
  float* op = out1 + (size_t)b*131072 + (size_t)ch2*1024 + s0 + hh*8;
  float4 v0; v0.x=vals[0]; v0.y=vals[1]; v0.z=vals[2]; v0.w=vals[3];
  float4 v1; v1.x=vals[4]; v1.y=vals[5]; v1.z=vals[6]; v1.w=vals[7];
  *(float4*)op = v0;
  *(float4*)(op+4) = v1;
}

extern "C" void kernel_launch(void* const* d_in, const int* in_sizes, int n_in,
                              void* d_out, int out_size, void* d_ws, size_t ws_size,
                              hipStream_t stream){
  (void)in_sizes; (void)n_in; (void)out_size; (void)ws_size;
  const float* xyz = (const float*)d_in[0];
  const float* pts = (const float*)d_in[1];
  const float* w1 = (const float*)d_in[2];  const float* b1 = (const float*)d_in[3];
  const float* g1 = (const float*)d_in[4];  const float* be1 = (const float*)d_in[5];
  const float* w2 = (const float*)d_in[6];  const float* b2 = (const float*)d_in[7];
  const float* g2 = (const float*)d_in[8];  const float* be2 = (const float*)d_in[9];
  const float* w3 = (const float*)d_in[10]; const float* b3 = (const float*)d_in[11];
  const float* g3 = (const float*)d_in[12]; const float* be3 = (const float*)d_in[13];

  float* out0 = (float*)d_out;                 // (B,3,1024)
  float* out1 = out0 + BATCH*3*SPTS;           // (B,128,1024)

  char* ws = (char*)d_ws;
  float*    ptsT = (float*)(ws + 0);                       // 33,554,432 B
  int*      idx  = (int*)  (ws + 34078720);                //  1,048,576 B
  uint16_t* y1   = (uint16_t*)(ws + 35127296);             // 33,554,432 B
  uint16_t* y2   = (uint16_t*)(ws + 68681728);             // 33,554,432 B
  uint16_t* y3   = (uint16_t*)(ws + 102236160);            // 67,108,864 B
  float*    stats = (float*)(ws + 169345024);              // 1536 floats
  float* gsum1 = stats;        float* gsq1 = stats + 128;
  float* gsum2 = stats + 256;  float* gsq2 = stats + 384;
  float* gsum3 = stats + 512;  float* gsq3 = stats + 640;
  float* scale1 = stats + 768; float* shift1 = stats + 896;
  float* scale2 = stats + 1024; float* shift2 = stats + 1152;
  float* scale3 = stats + 1280; float* shift3 = stats + 1408;

  hipMemsetAsync(stats, 0, 768*sizeof(float), stream);

  transpose_kernel<<<dim3(NPTS/32, DIMF/32, BATCH), 256, 0, stream>>>(pts, ptsT);
  fps_kernel<<<BATCH, 512, 0, stream>>>(xyz, out0);
  ball_kernel<<<BATCH*32, 256, 0, stream>>>(xyz, out0, idx);
  gemm1_kernel<<<MTOT/128, 256, 0, stream>>>(xyz, ptsT, idx, out0, w1, b1, y1);
  stats_kernel<64><<<512, 256, 0, stream>>>(y1, gsum1, gsq1);
  finalize_kernel<<<1, 128, 0, stream>>>(gsum1, gsq1, g1, be1, scale1, shift1, 64);
  gemm2_kernel<<<MTOT/128, 256, 0, stream>>>(y1, w2, b2, scale1, shift1, y2);
  stats_kernel<64><<<512, 256, 0, stream>>>(y2, gsum2, gsq2);
  finalize_kernel<<<1, 128, 0, stream>>>(gsum2, gsq2, g2, be2, scale2, shift2, 64);
  gemm3_kernel<<<MTOT/64, 256, 0, stream>>>(y2, w3, b3, scale2, shift2, y3);
  stats_kernel<128><<<512, 256, 0, stream>>>(y3, gsum3, gsq3);
  finalize_kernel<<<1, 128, 0, stream>>>(gsum3, gsq3, g3, be3, scale3, shift3, 128);
  maxpool_kernel<<<BATCH*(SPTS/16), 256, 0, stream>>>(y3, scale3, shift3, out1);
}